// Round 1
// baseline (2716.254 us; speedup 1.0000x reference)
//
#include <hip/hip_runtime.h>
#include <stdint.h>
#include <math.h>

typedef __attribute__((ext_vector_type(8))) short short8;
typedef __attribute__((ext_vector_type(4))) short short4v;
typedef __attribute__((ext_vector_type(4))) float f32x4;

__device__ __forceinline__ short f2bf(float f){
  union { float f; uint32_t u; } x; x.f = f;
  uint32_t r = x.u + 0x7fffu + ((x.u >> 16) & 1u);
  return (short)(r >> 16);
}
__device__ __forceinline__ float bf2f(short s){
  union { uint32_t u; float f; } x; x.u = ((uint32_t)(uint16_t)s) << 16;
  return x.f;
}

// ---------------- prep kernels ----------------

// Transposed, bf16, concatenated weights: W3T[j][k], j in [0,4096), k in [0,3072)
// k<1024 -> Wx[k][j]; k<2048 -> Wh[k-1024][j]; else Wattn[k-2048][j]
__global__ __launch_bounds__(256) void k_wt(const float* __restrict__ Wx,
                                            const float* __restrict__ Wh,
                                            const float* __restrict__ Wattn,
                                            short* __restrict__ W3T){
  __shared__ float tile[64][65];
  int bk = blockIdx.x % 48, bj = blockIdx.x / 48;
  int tx = threadIdx.x & 63, ty = threadIdx.x >> 6;   // ty 0..3
  int k0 = bk * 64, j0 = bj * 64;
  #pragma unroll
  for (int i = 0; i < 16; ++i){
    int kk = ty * 16 + i;
    int k = k0 + kk;
    const float* src = (k < 1024) ? (Wx + (size_t)k * 4096)
                     : (k < 2048) ? (Wh + (size_t)(k - 1024) * 4096)
                                  : (Wattn + (size_t)(k - 2048) * 4096);
    tile[kk][tx] = src[j0 + tx];
  }
  __syncthreads();
  #pragma unroll
  for (int i = 0; i < 16; ++i){
    int jj = ty * 16 + i;
    W3T[(size_t)(j0 + jj) * 3072 + k0 + tx] = f2bf(tile[tx][jj]);
  }
}

__global__ __launch_bounds__(256) void k_cast(const float* __restrict__ in,
                                              short* __restrict__ out, int n4){
  int i = blockIdx.x * 256 + threadIdx.x;
  if (i >= n4) return;
  float4 v = ((const float4*)in)[i];
  short4v o; o[0] = f2bf(v.x); o[1] = f2bf(v.y); o[2] = f2bf(v.z); o[3] = f2bf(v.w);
  *(short4v*)(out + (size_t)i * 4) = o;
}

// h0 = c0 = mean over L=16 of A
__global__ __launch_bounds__(256) void k_init(const float* __restrict__ A,
                                              float* __restrict__ c,
                                              short* __restrict__ hattn){
  int idx = blockIdx.x * 256 + threadIdx.x;    // N*H = 131072
  int n = idx >> 10, h = idx & 1023;
  const float* p = A + (size_t)idx * 16;
  float s = 0.f;
  #pragma unroll
  for (int l = 0; l < 16; ++l) s += p[l];
  s *= (1.f / 16.f);
  c[idx] = s;
  hattn[(size_t)n * 2048 + h] = f2bf(s);
}

// Precompute xWx (f32, [N*T][4096]) = xbf @ Wx part of W3T.  One wave = 64x64 tile.
__global__ __launch_bounds__(256) void k_xwx(const short* __restrict__ xbf,
                                             const short* __restrict__ W3T,
                                             float* __restrict__ xwx){
  const int lane = threadIdx.x & 63;
  const int wave = threadIdx.x >> 6;
  const int job = blockIdx.x * 4 + wave;       // 0..8191
  const int m0 = (job >> 6) * 64;              // 128 m-groups
  const int j0 = (job & 63) * 64;              // 64 j-groups
  const int ra = lane & 15;
  const int ks = (lane >> 4) * 8;

  f32x4 acc[4][4];
  #pragma unroll
  for (int mf = 0; mf < 4; ++mf)
    #pragma unroll
    for (int jf = 0; jf < 4; ++jf) acc[mf][jf] = f32x4{0.f,0.f,0.f,0.f};

  auto loadA = [&](int gk, int mf) -> short8 {
    return *(const short8*)(xbf + (size_t)(m0 + mf*16 + ra) * 1024 + gk + ks);
  };
  auto loadB = [&](int gk, int jf) -> short8 {
    return *(const short8*)(W3T + (size_t)(j0 + jf*16 + ra) * 3072 + gk + ks);
  };

  short8 aC[4], bC[4], aN[4], bN[4];
  #pragma unroll
  for (int mf = 0; mf < 4; ++mf) aC[mf] = loadA(0, mf);
  #pragma unroll
  for (int jf = 0; jf < 4; ++jf) bC[jf] = loadB(0, jf);

  for (int gk = 0; gk < 1024; gk += 32){
    bool more = (gk + 32) < 1024;
    if (more){
      #pragma unroll
      for (int mf = 0; mf < 4; ++mf) aN[mf] = loadA(gk + 32, mf);
      #pragma unroll
      for (int jf = 0; jf < 4; ++jf) bN[jf] = loadB(gk + 32, jf);
    }
    #pragma unroll
    for (int mf = 0; mf < 4; ++mf)
      #pragma unroll
      for (int jf = 0; jf < 4; ++jf)
        acc[mf][jf] = __builtin_amdgcn_mfma_f32_16x16x32_bf16(aC[mf], bC[jf], acc[mf][jf], 0, 0, 0);
    if (more){
      #pragma unroll
      for (int mf = 0; mf < 4; ++mf) aC[mf] = aN[mf];
      #pragma unroll
      for (int jf = 0; jf < 4; ++jf) bC[jf] = bN[jf];
    }
  }
  #pragma unroll
  for (int mf = 0; mf < 4; ++mf)
    #pragma unroll
    for (int jf = 0; jf < 4; ++jf)
      #pragma unroll
      for (int i = 0; i < 4; ++i){
        int row = m0 + mf*16 + (lane >> 4)*4 + i;
        int col = j0 + jf*16 + ra;
        xwx[(size_t)row * 4096 + col] = acc[mf][jf][i];
      }
}

// ---------------- per-step kernels ----------------

// One block per n. scores = (h . A[:,l]) / 32, softmax over 16, attn = A @ w -> bf16 into hattn cols 1024..2047
__global__ __launch_bounds__(256) void k_attn(const short* __restrict__ Abf,
                                              short* __restrict__ hattn){
  const int n = blockIdx.x;
  const int tid = threadIdx.x;
  float sc[16];
  #pragma unroll
  for (int l = 0; l < 16; ++l) sc[l] = 0.f;
  #pragma unroll
  for (int m = 0; m < 4; ++m){
    int hh = tid + m * 256;
    float hv = bf2f(hattn[(size_t)n * 2048 + hh]);
    const short8* ap = (const short8*)(Abf + ((size_t)n * 1024 + hh) * 16);
    short8 a0 = ap[0], a1 = ap[1];
    #pragma unroll
    for (int l = 0; l < 8; ++l){ sc[l] += hv * bf2f(a0[l]); sc[8+l] += hv * bf2f(a1[l]); }
  }
  #pragma unroll
  for (int off = 1; off < 64; off <<= 1)
    #pragma unroll
    for (int l = 0; l < 16; ++l) sc[l] += __shfl_xor(sc[l], off);
  __shared__ float sred[64];
  int w = tid >> 6, lane = tid & 63;
  if (lane == 0){
    #pragma unroll
    for (int l = 0; l < 16; ++l) sred[w * 16 + l] = sc[l];
  }
  __syncthreads();
  float s[16]; float mx = -1e30f;
  #pragma unroll
  for (int l = 0; l < 16; ++l){
    s[l] = (sred[l] + sred[16+l] + sred[32+l] + sred[48+l]) * 0.03125f;
    mx = fmaxf(mx, s[l]);
  }
  float sum = 0.f;
  #pragma unroll
  for (int l = 0; l < 16; ++l){ s[l] = expf(s[l] - mx); sum += s[l]; }
  float inv = 1.f / sum;
  #pragma unroll
  for (int l = 0; l < 16; ++l) s[l] *= inv;
  #pragma unroll
  for (int m = 0; m < 4; ++m){
    int hh = tid + m * 256;
    const short8* ap = (const short8*)(Abf + ((size_t)n * 1024 + hh) * 16);
    short8 a0 = ap[0], a1 = ap[1];
    float acc = 0.f;
    #pragma unroll
    for (int l = 0; l < 8; ++l){ acc += s[l] * bf2f(a0[l]); acc += s[8+l] * bf2f(a1[l]); }
    hattn[(size_t)n * 2048 + 1024 + hh] = f2bf(acc);
  }
}

// GEMM a = [segA0|segA1] @ W3T[:, wk0:wk0+K] (+xwx+b) fused with gates + LSTM update.
// One wave per block; wave tile = 32 rows x 16 u (4 gate fragments at j = g*1024+u).
__global__ __launch_bounds__(64) void k_step(
    const short* __restrict__ W3T,
    const short* __restrict__ segA0, int str0, int klen0,
    const short* __restrict__ segA1, int str1, int klen1,
    int wk0,
    const float* __restrict__ xwx,      // nullable
    const float* __restrict__ bias,
    float* __restrict__ c,
    short* __restrict__ hattn,
    float* __restrict__ out,
    int t)
{
  const int lane = threadIdx.x;
  const int bid = blockIdx.x;           // 256 blocks
  const int xcd = bid & 7;
  const int idx = bid >> 3;             // 0..31
  const int m0 = (idx & 3) * 32;
  const int u0 = (xcd * 8 + (idx >> 2)) * 16;
  const int ra = lane & 15;
  const int ks = (lane >> 4) * 8;
  const int K = klen0 + klen1;

  f32x4 acc[2][4];
  #pragma unroll
  for (int mf = 0; mf < 2; ++mf)
    #pragma unroll
    for (int g = 0; g < 4; ++g) acc[mf][g] = f32x4{0.f,0.f,0.f,0.f};

  auto loadA = [&](int gk, int mf) -> short8 {
    const short* base; int str, kk;
    if (gk < klen0){ base = segA0; str = str0; kk = gk; }
    else           { base = segA1; str = str1; kk = gk - klen0; }
    return *(const short8*)(base + (size_t)(m0 + mf*16 + ra) * str + kk + ks);
  };
  auto loadB = [&](int gk, int g) -> short8 {
    return *(const short8*)(W3T + (size_t)(g*1024 + u0 + ra) * 3072 + wk0 + gk + ks);
  };

  short8 aC[2], bC[4], aN[2], bN[4];
  #pragma unroll
  for (int mf = 0; mf < 2; ++mf) aC[mf] = loadA(0, mf);
  #pragma unroll
  for (int g = 0; g < 4; ++g) bC[g] = loadB(0, g);

  for (int gk = 0; gk < K; gk += 32){
    bool more = (gk + 32) < K;
    if (more){
      #pragma unroll
      for (int mf = 0; mf < 2; ++mf) aN[mf] = loadA(gk + 32, mf);
      #pragma unroll
      for (int g = 0; g < 4; ++g) bN[g] = loadB(gk + 32, g);
    }
    #pragma unroll
    for (int mf = 0; mf < 2; ++mf)
      #pragma unroll
      for (int g = 0; g < 4; ++g)
        acc[mf][g] = __builtin_amdgcn_mfma_f32_16x16x32_bf16(aC[mf], bC[g], acc[mf][g], 0, 0, 0);
    if (more){
      #pragma unroll
      for (int mf = 0; mf < 2; ++mf) aC[mf] = aN[mf];
      #pragma unroll
      for (int g = 0; g < 4; ++g) bC[g] = bN[g];
    }
  }

  const int u = u0 + ra;
  const float bi = bias[u], bfv = bias[1024 + u], bo = bias[2048 + u], bg = bias[3072 + u];
  #pragma unroll
  for (int mf = 0; mf < 2; ++mf){
    #pragma unroll
    for (int i = 0; i < 4; ++i){
      int n = m0 + mf*16 + (lane >> 4)*4 + i;
      float xi = 0.f, xf = 0.f, xo = 0.f, xg = 0.f;
      if (xwx){
        const float* p = xwx + ((size_t)(n * 64 + t)) * 4096;
        xi = p[u]; xf = p[1024 + u]; xo = p[2048 + u]; xg = p[3072 + u];
      }
      float av = acc[mf][0][i] + xi + bi;
      float fv = acc[mf][1][i] + xf + bfv;
      float ov = acc[mf][2][i] + xo + bo;
      float gv = acc[mf][3][i] + xg + bg;
      float ig = 1.f / (1.f + expf(-av));
      float fg = 1.f / (1.f + expf(-fv));
      float og = 1.f / (1.f + expf(-ov));
      float gg = tanhf(gv);
      float cn = fg * c[(size_t)n * 1024 + u] + ig * gg;
      c[(size_t)n * 1024 + u] = cn;
      float hn = og * tanhf(cn);
      hattn[(size_t)n * 2048 + u] = f2bf(hn);
      out[((size_t)n * 64 + t) * 1024 + u] = hn;
    }
  }
}

// ---------------- launch ----------------

extern "C" void kernel_launch(void* const* d_in, const int* in_sizes, int n_in,
                              void* d_out, int out_size, void* d_ws, size_t ws_size,
                              hipStream_t stream)
{
  const float* x     = (const float*)d_in[0];
  const float* A     = (const float*)d_in[1];
  const float* Wx    = (const float*)d_in[2];
  const float* Wh    = (const float*)d_in[3];
  const float* Wattn = (const float*)d_in[4];
  const float* b     = (const float*)d_in[5];
  float* out = (float*)d_out;
  char* ws = (char*)d_ws;

  short* W3T   = (short*)(ws + 0);            // 4096*3072*2  = 25165824
  short* Abf   = (short*)(ws + 25165824);     // 2097152*2    =  4194304
  short* xbf   = (short*)(ws + 29360128);     // 8388608*2    = 16777216
  short* hattn = (short*)(ws + 46137344);     // 128*2048*2   =   524288
  float* cbuf  = (float*)(ws + 46661632);     // 128*1024*4   =   524288
  float* xwx   = (float*)(ws + 47185920);     // 8192*4096*4  = 134217728 -> 181403648
  bool big = ws_size >= 181403648ull;

  hipLaunchKernelGGL(k_wt,   dim3(48 * 64), dim3(256), 0, stream, Wx, Wh, Wattn, W3T);
  hipLaunchKernelGGL(k_cast, dim3(2097152 / 256), dim3(256), 0, stream, x, xbf, 2097152);
  hipLaunchKernelGGL(k_cast, dim3(524288 / 256),  dim3(256), 0, stream, A, Abf, 524288);
  hipLaunchKernelGGL(k_init, dim3(512), dim3(256), 0, stream, A, cbuf, hattn);
  if (big)
    hipLaunchKernelGGL(k_xwx, dim3(2048), dim3(256), 0, stream, xbf, W3T, xwx);

  for (int t = 0; t < 64; ++t){
    hipLaunchKernelGGL(k_attn, dim3(128), dim3(256), 0, stream, Abf, hattn);
    if (big)
      hipLaunchKernelGGL(k_step, dim3(256), dim3(64), 0, stream,
                         W3T, hattn, 2048, 2048, hattn, 2048, 0, 1024,
                         xwx, b, cbuf, hattn, out, t);
    else
      hipLaunchKernelGGL(k_step, dim3(256), dim3(64), 0, stream,
                         W3T, xbf + t * 1024, 65536, 1024, hattn, 2048, 2048, 0,
                         (const float*)nullptr, b, cbuf, hattn, out, t);
  }
}

// Round 2
// 1508.734 us; speedup vs baseline: 1.8004x; 1.8004x over previous
//
#include <hip/hip_runtime.h>
#include <stdint.h>
#include <math.h>

typedef __attribute__((ext_vector_type(8))) short short8;
typedef __attribute__((ext_vector_type(4))) short short4v;
typedef __attribute__((ext_vector_type(4))) float f32x4;

typedef const __attribute__((address_space(1))) uint32_t* gas1_t;
typedef __attribute__((address_space(3))) uint32_t* las3_t;

__device__ __forceinline__ short f2bf(float f){
  union { float f; uint32_t u; } x; x.f = f;
  uint32_t r = x.u + 0x7fffu + ((x.u >> 16) & 1u);
  return (short)(r >> 16);
}
__device__ __forceinline__ float bf2f(short s){
  union { uint32_t u; float f; } x; x.u = ((uint32_t)(uint16_t)s) << 16;
  return x.f;
}

// ---------------- prep kernels ----------------

// Transposed, bf16, concatenated weights: W3T[j][k], j in [0,4096), k in [0,3072)
__global__ __launch_bounds__(256) void k_wt(const float* __restrict__ Wx,
                                            const float* __restrict__ Wh,
                                            const float* __restrict__ Wattn,
                                            short* __restrict__ W3T){
  __shared__ float tile[64][65];
  int bk = blockIdx.x % 48, bj = blockIdx.x / 48;
  int tx = threadIdx.x & 63, ty = threadIdx.x >> 6;   // ty 0..3
  int k0 = bk * 64, j0 = bj * 64;
  #pragma unroll
  for (int i = 0; i < 16; ++i){
    int kk = ty * 16 + i;
    int k = k0 + kk;
    const float* src = (k < 1024) ? (Wx + (size_t)k * 4096)
                     : (k < 2048) ? (Wh + (size_t)(k - 1024) * 4096)
                                  : (Wattn + (size_t)(k - 2048) * 4096);
    tile[kk][tx] = src[j0 + tx];
  }
  __syncthreads();
  #pragma unroll
  for (int i = 0; i < 16; ++i){
    int jj = ty * 16 + i;
    W3T[(size_t)(j0 + jj) * 3072 + k0 + tx] = f2bf(tile[tx][jj]);
  }
}

__global__ __launch_bounds__(256) void k_cast(const float* __restrict__ in,
                                              short* __restrict__ out, int n4){
  int i = blockIdx.x * 256 + threadIdx.x;
  if (i >= n4) return;
  float4 v = ((const float4*)in)[i];
  short4v o; o[0] = f2bf(v.x); o[1] = f2bf(v.y); o[2] = f2bf(v.z); o[3] = f2bf(v.w);
  *(short4v*)(out + (size_t)i * 4) = o;
}

// h0 = c0 = mean over L=16 of A
__global__ __launch_bounds__(256) void k_init(const float* __restrict__ A,
                                              float* __restrict__ c,
                                              short* __restrict__ hattn){
  int idx = blockIdx.x * 256 + threadIdx.x;    // N*H = 131072
  int n = idx >> 10, h = idx & 1023;
  const float* p = A + (size_t)idx * 16;
  float s = 0.f;
  #pragma unroll
  for (int l = 0; l < 16; ++l) s += p[l];
  s *= (1.f / 16.f);
  c[idx] = s;
  hattn[(size_t)n * 2048 + h] = f2bf(s);
}

// ---------------- xwx precompute: m97-style 128x128 tile GEMM ----------------
// xwx[8192][4096] = xbf[8192][1024] @ W3T[j][k<1024]^T
__global__ __launch_bounds__(256) void k_xwx(const short* __restrict__ xbf,
                                             const short* __restrict__ W3T,
                                             float* __restrict__ xwx){
  __shared__ short ldsA[128 * 64];   // 16 KB, row-major [row][chunk c of 8 elems], c pre-swizzled
  __shared__ short ldsB[128 * 64];
  const int tid  = threadIdx.x;
  const int lane = tid & 63;
  const int wave = tid >> 6;

  // bijective XCD swizzle: 2048 blocks, 8 XCDs, q = 256
  const int orig = blockIdx.x;
  const int wg = (orig & 7) * 256 + (orig >> 3);
  const int n_t = wg >> 6;          // 0..31 -> 4 B panels per XCD (1 MB, L2-fit)
  const int m_t = wg & 63;          // 0..63
  const int m0 = m_t * 128;
  const int n0 = n_t * 128;

  const int ra = lane & 15;
  const int q  = lane >> 4;

  f32x4 acc[4][4];
  #pragma unroll
  for (int mf = 0; mf < 4; ++mf)
    #pragma unroll
    for (int jf = 0; jf < 4; ++jf) acc[mf][jf] = f32x4{0.f,0.f,0.f,0.f};

  const int wm = wave >> 1;          // 0..1
  const int wn = wave & 1;           // 0..1

  for (int kt = 0; kt < 16; ++kt){
    const int kb = kt * 64;
    // stage A tile: rows m0..m0+127, k kb..kb+63.  16 wave-ops (4/wave).
    #pragma unroll
    for (int r = 0; r < 4; ++r){
      int id = (wave * 4 + r) * 64 + lane;
      int row = id >> 3, c = id & 7;
      int csrc = c ^ (row & 7);                       // inverse-swizzled SOURCE
      const short* src = xbf + (size_t)(m0 + row) * 1024 + kb + csrc * 8;
      short* dst = ldsA + (wave * 4 + r) * 512;       // linear dest, wave-uniform
      __builtin_amdgcn_global_load_lds((gas1_t)(const void*)src, (las3_t)(void*)dst, 16, 0, 0);
    }
    #pragma unroll
    for (int r = 0; r < 4; ++r){
      int id = (wave * 4 + r) * 64 + lane;
      int row = id >> 3, c = id & 7;
      int csrc = c ^ (row & 7);
      const short* src = W3T + (size_t)(n0 + row) * 3072 + kb + csrc * 8;
      short* dst = ldsB + (wave * 4 + r) * 512;
      __builtin_amdgcn_global_load_lds((gas1_t)(const void*)src, (las3_t)(void*)dst, 16, 0, 0);
    }
    asm volatile("s_waitcnt vmcnt(0)" ::: "memory");
    __syncthreads();

    #pragma unroll
    for (int kk = 0; kk < 64; kk += 32){
      const int cc = (kk >> 3) + q;                    // chunk 0..7
      short8 af[4], bfr[4];
      #pragma unroll
      for (int mf = 0; mf < 4; ++mf){
        int row = wm * 64 + mf * 16 + ra;
        af[mf] = *(const short8*)(ldsA + row * 64 + ((cc ^ (row & 7)) << 3));  // swizzled READ
      }
      #pragma unroll
      for (int jf = 0; jf < 4; ++jf){
        int row = wn * 64 + jf * 16 + ra;
        bfr[jf] = *(const short8*)(ldsB + row * 64 + ((cc ^ (row & 7)) << 3));
      }
      #pragma unroll
      for (int mf = 0; mf < 4; ++mf)
        #pragma unroll
        for (int jf = 0; jf < 4; ++jf)
          acc[mf][jf] = __builtin_amdgcn_mfma_f32_16x16x32_bf16(af[mf], bfr[jf], acc[mf][jf], 0, 0, 0);
    }
    __syncthreads();
  }

  #pragma unroll
  for (int mf = 0; mf < 4; ++mf)
    #pragma unroll
    for (int jf = 0; jf < 4; ++jf)
      #pragma unroll
      for (int i = 0; i < 4; ++i){
        int row = m0 + wm * 64 + mf * 16 + q * 4 + i;
        int col = n0 + wn * 64 + jf * 16 + ra;
        xwx[(size_t)row * 4096 + col] = acc[mf][jf][i];
      }
}

// ---------------- per-step kernels ----------------

__global__ __launch_bounds__(256) void k_attn(const short* __restrict__ Abf,
                                              short* __restrict__ hattn){
  const int n = blockIdx.x;
  const int tid = threadIdx.x;
  float sc[16];
  #pragma unroll
  for (int l = 0; l < 16; ++l) sc[l] = 0.f;
  #pragma unroll
  for (int m = 0; m < 4; ++m){
    int hh = tid + m * 256;
    float hv = bf2f(hattn[(size_t)n * 2048 + hh]);
    const short8* ap = (const short8*)(Abf + ((size_t)n * 1024 + hh) * 16);
    short8 a0 = ap[0], a1 = ap[1];
    #pragma unroll
    for (int l = 0; l < 8; ++l){ sc[l] += hv * bf2f(a0[l]); sc[8+l] += hv * bf2f(a1[l]); }
  }
  #pragma unroll
  for (int off = 1; off < 64; off <<= 1)
    #pragma unroll
    for (int l = 0; l < 16; ++l) sc[l] += __shfl_xor(sc[l], off);
  __shared__ float sred[64];
  int w = tid >> 6, lane = tid & 63;
  if (lane == 0){
    #pragma unroll
    for (int l = 0; l < 16; ++l) sred[w * 16 + l] = sc[l];
  }
  __syncthreads();
  float s[16]; float mx = -1e30f;
  #pragma unroll
  for (int l = 0; l < 16; ++l){
    s[l] = (sred[l] + sred[16+l] + sred[32+l] + sred[48+l]) * 0.03125f;
    mx = fmaxf(mx, s[l]);
  }
  float sum = 0.f;
  #pragma unroll
  for (int l = 0; l < 16; ++l){ s[l] = expf(s[l] - mx); sum += s[l]; }
  float inv = 1.f / sum;
  #pragma unroll
  for (int l = 0; l < 16; ++l) s[l] *= inv;
  #pragma unroll
  for (int m = 0; m < 4; ++m){
    int hh = tid + m * 256;
    const short8* ap = (const short8*)(Abf + ((size_t)n * 1024 + hh) * 16);
    short8 a0 = ap[0], a1 = ap[1];
    float acc = 0.f;
    #pragma unroll
    for (int l = 0; l < 8; ++l){ acc += s[l] * bf2f(a0[l]); acc += s[8+l] * bf2f(a1[l]); }
    hattn[(size_t)n * 2048 + 1024 + hh] = f2bf(acc);
  }
}

// GEMM a = [segA0|segA1] @ W3T[:, wk0:wk0+K] (+xwx+b) fused with gates + LSTM.
// 256 blocks x 4 waves; block tile = 32 rows x 16 u; waves K-split 4-way; LDS reduce.
__global__ __launch_bounds__(256) void k_step(
    const short* __restrict__ W3T,
    const short* __restrict__ segA0, int str0, int klen0,
    const short* __restrict__ segA1, int str1, int klen1,
    int wk0,
    const float* __restrict__ xwx,      // nullable
    const float* __restrict__ bias,
    float* __restrict__ c,
    short* __restrict__ hattn,
    float* __restrict__ out,
    int t)
{
  __shared__ float red[4][2][4][64][4];   // [srcwave][mf][g][lane][i]  = 32 KB
  const int lane = threadIdx.x & 63;
  const int wave = threadIdx.x >> 6;
  const int bid = blockIdx.x;           // 256 blocks
  const int xcd = bid & 7;
  const int idx = bid >> 3;             // 0..31
  const int m0 = (idx & 3) * 32;
  const int u0 = (xcd * 8 + (idx >> 2)) * 16;
  const int ra = lane & 15;
  const int q  = lane >> 4;
  const int ks = q * 8;
  const int K = klen0 + klen1;
  const int Kc = K >> 2;                // per-wave K chunk (512 big / 768 small)
  const int kw0 = wave * Kc;

  f32x4 acc[2][4];
  #pragma unroll
  for (int mf = 0; mf < 2; ++mf)
    #pragma unroll
    for (int g = 0; g < 4; ++g) acc[mf][g] = f32x4{0.f,0.f,0.f,0.f};

  auto loadA = [&](int gk, int mf) -> short8 {
    const short* base; int str, kk;
    if (gk < klen0){ base = segA0; str = str0; kk = gk; }
    else           { base = segA1; str = str1; kk = gk - klen0; }
    return *(const short8*)(base + (size_t)(m0 + mf*16 + ra) * str + kk + ks);
  };
  auto loadB = [&](int gk, int g) -> short8 {
    return *(const short8*)(W3T + (size_t)(g*1024 + u0 + ra) * 3072 + wk0 + gk + ks);
  };

  short8 aC[2], bC[4], aN[2], bN[4];
  #pragma unroll
  for (int mf = 0; mf < 2; ++mf) aC[mf] = loadA(kw0, mf);
  #pragma unroll
  for (int g = 0; g < 4; ++g) bC[g] = loadB(kw0, g);

  for (int gk = kw0; gk < kw0 + Kc; gk += 32){
    bool more = (gk + 32) < (kw0 + Kc);
    if (more){
      #pragma unroll
      for (int mf = 0; mf < 2; ++mf) aN[mf] = loadA(gk + 32, mf);
      #pragma unroll
      for (int g = 0; g < 4; ++g) bN[g] = loadB(gk + 32, g);
    }
    #pragma unroll
    for (int mf = 0; mf < 2; ++mf)
      #pragma unroll
      for (int g = 0; g < 4; ++g)
        acc[mf][g] = __builtin_amdgcn_mfma_f32_16x16x32_bf16(aC[mf], bC[g], acc[mf][g], 0, 0, 0);
    if (more){
      #pragma unroll
      for (int mf = 0; mf < 2; ++mf) aC[mf] = aN[mf];
      #pragma unroll
      for (int g = 0; g < 4; ++g) bC[g] = bN[g];
    }
  }

  // cross-wave reduction
  #pragma unroll
  for (int mf = 0; mf < 2; ++mf)
    #pragma unroll
    for (int g = 0; g < 4; ++g)
      *(f32x4*)&red[wave][mf][g][lane][0] = acc[mf][g];
  __syncthreads();

  if (wave < 2){
    const int mf = wave;
    f32x4 tot[4];
    #pragma unroll
    for (int g = 0; g < 4; ++g){
      f32x4 s0 = *(const f32x4*)&red[0][mf][g][lane][0];
      f32x4 s1 = *(const f32x4*)&red[1][mf][g][lane][0];
      f32x4 s2 = *(const f32x4*)&red[2][mf][g][lane][0];
      f32x4 s3 = *(const f32x4*)&red[3][mf][g][lane][0];
      tot[g] = (s0 + s1) + (s2 + s3);
    }
    const int u = u0 + ra;
    const float bi = bias[u], bfv = bias[1024 + u], bo = bias[2048 + u], bg = bias[3072 + u];
    #pragma unroll
    for (int i = 0; i < 4; ++i){
      int n = m0 + mf*16 + q*4 + i;
      float xi = 0.f, xf = 0.f, xo = 0.f, xg = 0.f;
      if (xwx){
        const float* p = xwx + ((size_t)(n * 64 + t)) * 4096;
        xi = p[u]; xf = p[1024 + u]; xo = p[2048 + u]; xg = p[3072 + u];
      }
      float av = tot[0][i] + xi + bi;
      float fv = tot[1][i] + xf + bfv;
      float ov = tot[2][i] + xo + bo;
      float gv = tot[3][i] + xg + bg;
      float ig = 1.f / (1.f + expf(-av));
      float fg = 1.f / (1.f + expf(-fv));
      float og = 1.f / (1.f + expf(-ov));
      float gg = tanhf(gv);
      float cn = fg * c[(size_t)n * 1024 + u] + ig * gg;
      c[(size_t)n * 1024 + u] = cn;
      float hn = og * tanhf(cn);
      hattn[(size_t)n * 2048 + u] = f2bf(hn);
      out[((size_t)n * 64 + t) * 1024 + u] = hn;
    }
  }
}

// ---------------- launch ----------------

extern "C" void kernel_launch(void* const* d_in, const int* in_sizes, int n_in,
                              void* d_out, int out_size, void* d_ws, size_t ws_size,
                              hipStream_t stream)
{
  const float* x     = (const float*)d_in[0];
  const float* A     = (const float*)d_in[1];
  const float* Wx    = (const float*)d_in[2];
  const float* Wh    = (const float*)d_in[3];
  const float* Wattn = (const float*)d_in[4];
  const float* b     = (const float*)d_in[5];
  float* out = (float*)d_out;
  char* ws = (char*)d_ws;

  short* W3T   = (short*)(ws + 0);            // 4096*3072*2  = 25165824
  short* Abf   = (short*)(ws + 25165824);     // 2097152*2    =  4194304
  short* xbf   = (short*)(ws + 29360128);     // 8388608*2    = 16777216
  short* hattn = (short*)(ws + 46137344);     // 128*2048*2   =   524288
  float* cbuf  = (float*)(ws + 46661632);     // 128*1024*4   =   524288
  float* xwx   = (float*)(ws + 47185920);     // 8192*4096*4  = 134217728 -> 181403648
  bool big = ws_size >= 181403648ull;

  hipLaunchKernelGGL(k_wt,   dim3(48 * 64), dim3(256), 0, stream, Wx, Wh, Wattn, W3T);
  hipLaunchKernelGGL(k_cast, dim3(2097152 / 256), dim3(256), 0, stream, x, xbf, 2097152);
  hipLaunchKernelGGL(k_cast, dim3(524288 / 256),  dim3(256), 0, stream, A, Abf, 524288);
  hipLaunchKernelGGL(k_init, dim3(512), dim3(256), 0, stream, A, cbuf, hattn);
  if (big)
    hipLaunchKernelGGL(k_xwx, dim3(2048), dim3(256), 0, stream, xbf, W3T, xwx);

  for (int t = 0; t < 64; ++t){
    hipLaunchKernelGGL(k_attn, dim3(128), dim3(256), 0, stream, Abf, hattn);
    if (big)
      hipLaunchKernelGGL(k_step, dim3(256), dim3(256), 0, stream,
                         W3T, hattn, 2048, 2048, hattn, 2048, 0, 1024,
                         xwx, b, cbuf, hattn, out, t);
    else
      hipLaunchKernelGGL(k_step, dim3(256), dim3(256), 0, stream,
                         W3T, xbf + t * 1024, 65536, 1024, hattn, 2048, 2048, 0,
                         (const float*)nullptr, b, cbuf, hattn, out, t);
  }
}